// Round 14
// baseline (2487.495 us; speedup 1.0000x reference)
//
#include <hip/hip_runtime.h>

#define EPS 1e-5f
#define PITCH 528   // bytes per LDS row (264 bf16); 132 words % 32 banks = 4

typedef __attribute__((ext_vector_type(8))) short s16x8;
typedef __attribute__((ext_vector_type(4))) short s16x4;
typedef __attribute__((ext_vector_type(2))) short s16x2;
typedef __attribute__((ext_vector_type(4))) float f32x4;

static __device__ __forceinline__ short f2bf(float x) {
    union { float f; unsigned u; } v; v.f = x;
    return (short)((v.u + 0x7fffu + ((v.u >> 16) & 1u)) >> 16);  // RNE
}
static __device__ __forceinline__ float bf2f(short h) {
    union { float f; unsigned u; } v; v.u = ((unsigned)(unsigned short)h) << 16;
    return v.f;
}
struct bfhl { short hi, lo; };
// exact split: x = hi + lo + r, |r| <= 2^-17 |x|; bf16 lo never denormal
static __device__ __forceinline__ bfhl splitbf(float x) {
    bfhl r; r.hi = f2bf(x); r.lo = f2bf(x - bf2f(r.hi)); return r;
}

// ---- prep: repack w1,w2 (fp32 [K][N]) into split-bf16 MFMA A-fragments of W^T ----
// A-frag for tile (ft,ks): lane l, elem j <- W[ks*32 + (l>>4)*8 + j][ft*16 + (l&15)]
__global__ __launch_bounds__(256) void prep_weights(
    const float* __restrict__ w1, const float* __restrict__ w2,
    short* __restrict__ wb1h, short* __restrict__ wb1l,
    short* __restrict__ wb2h, short* __restrict__ wb2l)
{
    const int t = blockIdx.x * 256 + threadIdx.x;
    const int lane = t & 63, frag = t >> 6;
    const int row0 = ((frag & 7) * 32) + ((lane >> 4) * 8);   // k base
    short hi[8], lo[8];
    if (frag < 128) {                 // w1: 16 ft x 8 ks
        const int col = (frag >> 3) * 16 + (lane & 15);
        #pragma unroll
        for (int j = 0; j < 8; ++j) {
            const bfhl r = splitbf(w1[(row0 + j) * 256 + col]);
            hi[j] = r.hi; lo[j] = r.lo;
        }
        *reinterpret_cast<s16x8*>(&wb1h[frag * 512 + lane * 8]) = *reinterpret_cast<s16x8*>(hi);
        *reinterpret_cast<s16x8*>(&wb1l[frag * 512 + lane * 8]) = *reinterpret_cast<s16x8*>(lo);
    } else if (frag < 192) {          // w2: 8 ft x 8 ks
        const int f = frag - 128;
        const int col = (f >> 3) * 16 + (lane & 15);
        #pragma unroll
        for (int j = 0; j < 8; ++j) {
            const bfhl r = splitbf(w2[(row0 + j) * 128 + col]);
            hi[j] = r.hi; lo[j] = r.lo;
        }
        *reinterpret_cast<s16x8*>(&wb2h[f * 512 + lane * 8]) = *reinterpret_cast<s16x8*>(hi);
        *reinterpret_cast<s16x8*>(&wb2l[f * 512 + lane * 8]) = *reinterpret_cast<s16x8*>(lo);
    }
}

// ---- fused MLP: persistent blocks (grid=256, 1/CU), 64 edges/tile, 1024 thr ----
// acc = Wh·Hl + Wl·Hh + Wh·Hh  (dropped Wl·Hl <= 2^-17 rel)
// HARD CONSTRAINT (empirical, R2-R12): LDS > 80KB so only ONE block/CU.
// Weight A-fragments live in REGISTERS across all tiles (loaded once).
// GEMM1: wave (eg=w>>3, fg=w&7) owns ft {2fg,2fg+1} x edge-tiles {2eg,2eg+1}
//   -> halves LDS B-traffic vs 1-ft/wave (each B-read feeds 6 MFMAs).
// GEMM2: wave (ft2=w>>1, hf=w&1) as before.
__global__ __launch_bounds__(1024, 4) void edge_mlp(
    const float* __restrict__ x, const int* __restrict__ ei,
    const float* __restrict__ ln0_g, const float* __restrict__ ln0_b,
    const short* __restrict__ wb1h, const short* __restrict__ wb1l,
    const float* __restrict__ b1,
    const float* __restrict__ ln1_g, const float* __restrict__ ln1_b,
    const short* __restrict__ wb2h, const short* __restrict__ wb2l,
    const float* __restrict__ b2,
    const float* __restrict__ ln2_g, const float* __restrict__ ln2_b,
    const float* __restrict__ wp, const float* __restrict__ bp,
    const float* __restrict__ ww, const float* __restrict__ bw,
    float* __restrict__ out, int E, int ntiles)
{
    __shared__ __align__(16) short h0h[64 * 264];   // 33.8KB each; ~144KB total
    __shared__ __align__(16) short h0l[64 * 264];
    __shared__ __align__(16) short h1h[64 * 264];
    __shared__ __align__(16) short h1l[64 * 264];
    __shared__ __align__(8) float red[16][64][2];
    __shared__ __align__(8) float stat[64][2];
    __shared__ int sidx[64][2];

    const int tid = threadIdx.x, lane = tid & 63, w = tid >> 6;   // w in 0..15
    const int g = lane >> 4, c15 = lane & 15;
    const int fg = w & 7, eg = w >> 3;      // GEMM1 mapping
    const int ft2 = w >> 1, hf = w & 1;     // GEMM2 mapping

    // ---- persistent weight fragments (loaded once, reused for all tiles) ----
    s16x8 a1h[2][8], a1l[2][8], a2h[8], a2l[8];
    #pragma unroll
    for (int mt = 0; mt < 2; ++mt)
        #pragma unroll
        for (int ks = 0; ks < 8; ++ks) {
            const int fo = (((2 * fg + mt) * 8 + ks) * 512) + lane * 8;
            a1h[mt][ks] = *reinterpret_cast<const s16x8*>(&wb1h[fo]);
            a1l[mt][ks] = *reinterpret_cast<const s16x8*>(&wb1l[fo]);
        }
    #pragma unroll
    for (int ks = 0; ks < 8; ++ks) {
        const int fo = ((ft2 * 8 + ks) * 512) + lane * 8;
        a2h[ks] = *reinterpret_cast<const s16x8*>(&wb2h[fo]);
        a2l[ks] = *reinterpret_cast<const s16x8*>(&wb2l[fo]);
    }

    for (int t = blockIdx.x; t < ntiles; t += gridDim.x) {
        const long base = (long)t * 64;

        if (tid < 128) {
            const int e = tid >> 1, s = tid & 1;
            const long idx = base + e;
            sidx[e][s] = (idx < E) ? ei[(long)s * E + idx] : 0;
        }
        __syncthreads();

        // ---------- P1: gather + feats + LN0 -> h0h/h0l (wave w: edges w*4..w*4+3) ----------
        {
            const int c = 2 * lane;
            const float ga = ln0_g[c], gb = ln0_g[c + 1], gc = ln0_g[128 + c], gd = ln0_g[129 + c];
            const float ba = ln0_b[c], bb = ln0_b[c + 1], bc = ln0_b[128 + c], bd = ln0_b[129 + c];
            char* hhc = (char*)h0h;
            char* hlc = (char*)h0l;
            #pragma unroll
            for (int e8 = 0; e8 < 4; ++e8) {
                const int e = w * 4 + e8;
                const float2 sv = *reinterpret_cast<const float2*>(&x[(long)sidx[e][0] * 128 + c]);
                const float2 dv = *reinterpret_cast<const float2*>(&x[(long)sidx[e][1] * 128 + c]);
                const float a0 = sv.x + dv.x, a1 = sv.y + dv.y;
                const float m0 = sv.x * dv.x, m1 = sv.y * dv.y;
                float s = a0 + a1 + m0 + m1;
                float q = a0 * a0 + a1 * a1 + m0 * m0 + m1 * m1;
                #pragma unroll
                for (int o = 32; o; o >>= 1) { s += __shfl_xor(s, o); q += __shfl_xor(q, o); }
                const float mu = s * (1.f / 256.f);
                const float rs = rsqrtf(q * (1.f / 256.f) - mu * mu + EPS);
                const bfhl r0 = splitbf((a0 - mu) * rs * ga + ba);
                const bfhl r1 = splitbf((a1 - mu) * rs * gb + bb);
                const bfhl r2 = splitbf((m0 - mu) * rs * gc + bc);
                const bfhl r3 = splitbf((m1 - mu) * rs * gd + bd);
                s16x2 p0h, p0l, p1h, p1l;
                p0h[0] = r0.hi; p0l[0] = r0.lo;
                p0h[1] = r1.hi; p0l[1] = r1.lo;
                p1h[0] = r2.hi; p1l[0] = r2.lo;
                p1h[1] = r3.hi; p1l[1] = r3.lo;
                const int o0 = e * PITCH + 4 * lane;
                const int o1 = e * PITCH + 256 + 4 * lane;
                *reinterpret_cast<s16x2*>(hhc + o0) = p0h;
                *reinterpret_cast<s16x2*>(hhc + o1) = p1h;
                *reinterpret_cast<s16x2*>(hlc + o0) = p0l;
                *reinterpret_cast<s16x2*>(hlc + o1) = p1l;
            }
        }
        __syncthreads();

        // ---------- P2: GEMM1  D[feat 256][edge 64] ----------
        f32x4 acc[2][2] = {};   // [mt][ntl]
        {
            const char* hhc = (const char*)h0h;
            const char* hlc = (const char*)h0l;
            #pragma unroll
            for (int ks = 0; ks < 8; ++ks) {
                const int kb = ks * 64 + g * 16;
                #pragma unroll
                for (int ntl = 0; ntl < 2; ++ntl) {
                    const int e = (2 * eg + ntl) * 16 + c15;
                    const int off = e * PITCH + kb;
                    const s16x8 bh = *reinterpret_cast<const s16x8*>(hhc + off);
                    const s16x8 bl = *reinterpret_cast<const s16x8*>(hlc + off);
                    #pragma unroll
                    for (int mt = 0; mt < 2; ++mt) {
                        acc[mt][ntl] = __builtin_amdgcn_mfma_f32_16x16x32_bf16(a1h[mt][ks], bl, acc[mt][ntl], 0, 0, 0);
                        acc[mt][ntl] = __builtin_amdgcn_mfma_f32_16x16x32_bf16(a1l[mt][ks], bh, acc[mt][ntl], 0, 0, 0);
                        acc[mt][ntl] = __builtin_amdgcn_mfma_f32_16x16x32_bf16(a1h[mt][ks], bh, acc[mt][ntl], 0, 0, 0);
                    }
                }
            }
        }

        // ---------- P3: bias + LN1 stats + apply + relu -> h1h/h1l ----------
        {
            float bi[2][4];
            *reinterpret_cast<float4*>(bi[0]) = *reinterpret_cast<const float4*>(&b1[(2 * fg + 0) * 16 + g * 4]);
            *reinterpret_cast<float4*>(bi[1]) = *reinterpret_cast<const float4*>(&b1[(2 * fg + 1) * 16 + g * 4]);
            float s[2], q[2];
            #pragma unroll
            for (int ntl = 0; ntl < 2; ++ntl) { s[ntl] = 0.f; q[ntl] = 0.f; }
            #pragma unroll
            for (int mt = 0; mt < 2; ++mt)
                #pragma unroll
                for (int ntl = 0; ntl < 2; ++ntl)
                    #pragma unroll
                    for (int r = 0; r < 4; ++r) {
                        const float v2 = acc[mt][ntl][r] + bi[mt][r];
                        acc[mt][ntl][r] = v2; s[ntl] += v2; q[ntl] += v2 * v2;
                    }
            #pragma unroll
            for (int ntl = 0; ntl < 2; ++ntl) {
                s[ntl] += __shfl_xor(s[ntl], 16); q[ntl] += __shfl_xor(q[ntl], 16);
                s[ntl] += __shfl_xor(s[ntl], 32); q[ntl] += __shfl_xor(q[ntl], 32);
            }
            if ((g >> 1) == eg) {   // lane == edge for nt = g, ntl = g&1
                red[w][lane][0] = (g & 1) ? s[1] : s[0];
                red[w][lane][1] = (g & 1) ? q[1] : q[0];
            }
        }
        __syncthreads();
        if (tid < 64) {
            const int hE = tid >> 5;
            float S = 0.f, Q = 0.f;
            #pragma unroll
            for (int f = 0; f < 8; ++f) { S += red[hE * 8 + f][tid][0]; Q += red[hE * 8 + f][tid][1]; }
            const float mu = S * (1.f / 256.f);
            stat[tid][0] = mu;
            stat[tid][1] = rsqrtf(Q * (1.f / 256.f) - mu * mu + EPS);
        }
        __syncthreads();
        {
            float gv[2][4], bv[2][4];
            *reinterpret_cast<float4*>(gv[0]) = *reinterpret_cast<const float4*>(&ln1_g[(2 * fg + 0) * 16 + g * 4]);
            *reinterpret_cast<float4*>(gv[1]) = *reinterpret_cast<const float4*>(&ln1_g[(2 * fg + 1) * 16 + g * 4]);
            *reinterpret_cast<float4*>(bv[0]) = *reinterpret_cast<const float4*>(&ln1_b[(2 * fg + 0) * 16 + g * 4]);
            *reinterpret_cast<float4*>(bv[1]) = *reinterpret_cast<const float4*>(&ln1_b[(2 * fg + 1) * 16 + g * 4]);
            char* hhc = (char*)h1h;
            char* hlc = (char*)h1l;
            #pragma unroll
            for (int mt = 0; mt < 2; ++mt)
                #pragma unroll
                for (int ntl = 0; ntl < 2; ++ntl) {
                    const int e = (2 * eg + ntl) * 16 + c15;
                    const float2 st = *reinterpret_cast<const float2*>(stat[e]);
                    s16x4 ph, pl;
                    #pragma unroll
                    for (int r = 0; r < 4; ++r) {
                        const bfhl rr = splitbf(fmaxf((acc[mt][ntl][r] - st.x) * st.y * gv[mt][r] + bv[mt][r], 0.f));
                        ph[r] = rr.hi; pl[r] = rr.lo;
                    }
                    const int off = e * PITCH + ((2 * fg + mt) * 16 + g * 4) * 2;
                    *reinterpret_cast<s16x4*>(hhc + off) = ph;
                    *reinterpret_cast<s16x4*>(hlc + off) = pl;
                }
        }
        __syncthreads();

        // ---------- P4: GEMM2  D[feat 128][edge 64] ----------
        f32x4 acc2[2] = {};
        {
            const char* hhc = (const char*)h1h;
            const char* hlc = (const char*)h1l;
            #pragma unroll
            for (int ks = 0; ks < 8; ++ks) {
                const int kb = ks * 64 + g * 16;
                #pragma unroll
                for (int ntl = 0; ntl < 2; ++ntl) {
                    const int e = (2 * hf + ntl) * 16 + c15;
                    const int off = e * PITCH + kb;
                    const s16x8 bh = *reinterpret_cast<const s16x8*>(hhc + off);
                    const s16x8 bl = *reinterpret_cast<const s16x8*>(hlc + off);
                    acc2[ntl] = __builtin_amdgcn_mfma_f32_16x16x32_bf16(a2h[ks], bl, acc2[ntl], 0, 0, 0);
                    acc2[ntl] = __builtin_amdgcn_mfma_f32_16x16x32_bf16(a2l[ks], bh, acc2[ntl], 0, 0, 0);
                    acc2[ntl] = __builtin_amdgcn_mfma_f32_16x16x32_bf16(a2h[ks], bh, acc2[ntl], 0, 0, 0);
                }
            }
        }

        // ---------- P5: bias + LN2 stats ----------
        {
            float bi[4];
            *reinterpret_cast<float4*>(bi) = *reinterpret_cast<const float4*>(&b2[ft2 * 16 + g * 4]);
            float s[2], q[2];
            #pragma unroll
            for (int ntl = 0; ntl < 2; ++ntl) {
                s[ntl] = 0.f; q[ntl] = 0.f;
                #pragma unroll
                for (int r = 0; r < 4; ++r) {
                    const float v2 = acc2[ntl][r] + bi[r];
                    acc2[ntl][r] = v2; s[ntl] += v2; q[ntl] += v2 * v2;
                }
            }
            #pragma unroll
            for (int ntl = 0; ntl < 2; ++ntl) {
                s[ntl] += __shfl_xor(s[ntl], 16); q[ntl] += __shfl_xor(q[ntl], 16);
                s[ntl] += __shfl_xor(s[ntl], 32); q[ntl] += __shfl_xor(q[ntl], 32);
            }
            if ((g >> 1) == hf) {
                red[w][lane][0] = (g & 1) ? s[1] : s[0];
                red[w][lane][1] = (g & 1) ? q[1] : q[0];
            }
        }
        __syncthreads();
        if (tid < 64) {
            const int hE = tid >> 5;
            float S = 0.f, Q = 0.f;
            #pragma unroll
            for (int w2 = 0; w2 < 16; w2 += 2) { S += red[w2 + hE][tid][0]; Q += red[w2 + hE][tid][1]; }
            const float mu = S * (1.f / 128.f);
            stat[tid][0] = mu;
            stat[tid][1] = rsqrtf(Q * (1.f / 128.f) - mu * mu + EPS);
        }
        __syncthreads();

        // ---------- P6: LN2 apply + relu + heads ----------
        {
            float gv[4], bv[4], pv[4], wv[4];
            *reinterpret_cast<float4*>(gv) = *reinterpret_cast<const float4*>(&ln2_g[ft2 * 16 + g * 4]);
            *reinterpret_cast<float4*>(bv) = *reinterpret_cast<const float4*>(&ln2_b[ft2 * 16 + g * 4]);
            *reinterpret_cast<float4*>(pv) = *reinterpret_cast<const float4*>(&wp[ft2 * 16 + g * 4]);
            *reinterpret_cast<float4*>(wv) = *reinterpret_cast<const float4*>(&ww[ft2 * 16 + g * 4]);
            float pp[2], ws2[2];
            #pragma unroll
            for (int ntl = 0; ntl < 2; ++ntl) {
                const int e = (2 * hf + ntl) * 16 + c15;
                const float2 st = *reinterpret_cast<const float2*>(stat[e]);
                pp[ntl] = 0.f; ws2[ntl] = 0.f;
                #pragma unroll
                for (int r = 0; r < 4; ++r) {
                    const float tt = fmaxf((acc2[ntl][r] - st.x) * st.y * gv[r] + bv[r], 0.f);
                    pp[ntl] += tt * pv[r]; ws2[ntl] += tt * wv[r];
                }
            }
            #pragma unroll
            for (int ntl = 0; ntl < 2; ++ntl) {
                pp[ntl] += __shfl_xor(pp[ntl], 16); ws2[ntl] += __shfl_xor(ws2[ntl], 16);
                pp[ntl] += __shfl_xor(pp[ntl], 32); ws2[ntl] += __shfl_xor(ws2[ntl], 32);
            }
            if ((g >> 1) == hf) {
                red[w][lane][0] = (g & 1) ? pp[1] : pp[0];
                red[w][lane][1] = (g & 1) ? ws2[1] : ws2[0];
            }
        }
        __syncthreads();
        if (tid < 64 && base + tid < E) {
            const int hE = tid >> 5;
            float P = bp[0], W = bw[0];
            #pragma unroll
            for (int w2 = 0; w2 < 16; w2 += 2) { P += red[w2 + hE][tid][0]; W += red[w2 + hE][tid][1]; }
            out[base + tid] = P;                         // logits
            out[(long)E + base + tid] = fmaxf(W, 0.f);   // relu'd weights
        }
        __syncthreads();   // red/stat safe for next tile's writers
    }
}

extern "C" void kernel_launch(void* const* d_in, const int* in_sizes, int n_in,
                              void* d_out, int out_size, void* d_ws, size_t ws_size,
                              hipStream_t stream) {
    const float* x     = (const float*)d_in[0];
    const int*   ei    = (const int*)  d_in[1];
    const float* ln0_g = (const float*)d_in[2];
    const float* ln0_b = (const float*)d_in[3];
    const float* w1    = (const float*)d_in[4];
    const float* b1    = (const float*)d_in[5];
    const float* ln1_g = (const float*)d_in[6];
    const float* ln1_b = (const float*)d_in[7];
    const float* w2    = (const float*)d_in[8];
    const float* b2    = (const float*)d_in[9];
    const float* ln2_g = (const float*)d_in[10];
    const float* ln2_b = (const float*)d_in[11];
    const float* wp    = (const float*)d_in[12];
    const float* bp    = (const float*)d_in[13];
    const float* ww    = (const float*)d_in[14];
    const float* bw    = (const float*)d_in[15];

    short* wb1h = (short*)d_ws;             // 128 frags * 512
    short* wb1l = wb1h + 128 * 512;
    short* wb2h = wb1l + 128 * 512;         // 64 frags * 512
    short* wb2l = wb2h + 64 * 512;          // total 384KB

    const int E = in_sizes[1] / 2;
    const int ntiles = (E + 63) / 64;
    prep_weights<<<48, 256, 0, stream>>>(w1, w2, wb1h, wb1l, wb2h, wb2l);
    edge_mlp<<<256, 1024, 0, stream>>>(x, ei, ln0_g, ln0_b, wb1h, wb1l, b1,
                                       ln1_g, ln1_b, wb2h, wb2l, b2, ln2_g, ln2_b,
                                       wp, bp, ww, bw, (float*)d_out, E, ntiles);
}

// Round 15
// 877.733 us; speedup vs baseline: 2.8340x; 2.8340x over previous
//
#include <hip/hip_runtime.h>

#define EPS 1e-5f
#define PITCH 528   // bytes per LDS row (264 bf16); 132 words % 32 banks = 4

typedef __attribute__((ext_vector_type(8))) short s16x8;
typedef __attribute__((ext_vector_type(4))) short s16x4;
typedef __attribute__((ext_vector_type(2))) short s16x2;
typedef __attribute__((ext_vector_type(4))) float f32x4;
typedef __attribute__((ext_vector_type(16))) float f32x16;

static __device__ __forceinline__ short f2bf(float x) {
    union { float f; unsigned u; } v; v.f = x;
    return (short)((v.u + 0x7fffu + ((v.u >> 16) & 1u)) >> 16);  // RNE
}
static __device__ __forceinline__ float bf2f(short h) {
    union { float f; unsigned u; } v; v.u = ((unsigned)(unsigned short)h) << 16;
    return v.f;
}
struct bfhl { short hi, lo; };
// exact split: x = hi + lo + r, |r| <= 2^-17 |x|; bf16 lo never denormal
static __device__ __forceinline__ bfhl splitbf(float x) {
    bfhl r; r.hi = f2bf(x); r.lo = f2bf(x - bf2f(r.hi)); return r;
}

// ---- prep: repack weights into split-bf16 MFMA A-fragments of W^T ----
// w1 -> 32x32x16 frags: (ft in 0..7, ks in 0..15):
//   lane l, elem j <- W1[ks*16 + (l>>5)*8 + j][ft*32 + (l&31)]
// w2 -> 16x16x32 frags: (ft in 0..7, ks in 0..7):
//   lane l, elem j <- W2[ks*32 + (l>>4)*8 + j][ft*16 + (l&15)]
__global__ __launch_bounds__(256) void prep_weights(
    const float* __restrict__ w1, const float* __restrict__ w2,
    short* __restrict__ wb1h, short* __restrict__ wb1l,
    short* __restrict__ wb2h, short* __restrict__ wb2l)
{
    const int t = blockIdx.x * 256 + threadIdx.x;
    const int lane = t & 63, frag = t >> 6;
    short hi[8], lo[8];
    if (frag < 128) {                 // w1: 8 ft32 x 16 ks16
        const int ks = frag & 15;
        const int row0 = ks * 16 + (lane >> 5) * 8;
        const int col = (frag >> 4) * 32 + (lane & 31);
        #pragma unroll
        for (int j = 0; j < 8; ++j) {
            const bfhl r = splitbf(w1[(row0 + j) * 256 + col]);
            hi[j] = r.hi; lo[j] = r.lo;
        }
        *reinterpret_cast<s16x8*>(&wb1h[frag * 512 + lane * 8]) = *reinterpret_cast<s16x8*>(hi);
        *reinterpret_cast<s16x8*>(&wb1l[frag * 512 + lane * 8]) = *reinterpret_cast<s16x8*>(lo);
    } else if (frag < 192) {          // w2: 8 ft16 x 8 ks32
        const int f = frag - 128;
        const int row0 = ((f & 7) * 32) + ((lane >> 4) * 8);
        const int col = (f >> 3) * 16 + (lane & 15);
        #pragma unroll
        for (int j = 0; j < 8; ++j) {
            const bfhl r = splitbf(w2[(row0 + j) * 128 + col]);
            hi[j] = r.hi; lo[j] = r.lo;
        }
        *reinterpret_cast<s16x8*>(&wb2h[f * 512 + lane * 8]) = *reinterpret_cast<s16x8*>(hi);
        *reinterpret_cast<s16x8*>(&wb2l[f * 512 + lane * 8]) = *reinterpret_cast<s16x8*>(lo);
    }
}

// ---- fused MLP: 64 edges/block, 1024 thr (16 waves), split-bf16 3-MFMA GEMMs ----
// acc = Wh·Hl + Wl·Hh + Wh·Hh  (dropped Wl·Hl <= 2^-17 rel)
// HARD CONSTRAINT (empirical, R2-R12): LDS > 80KB so only ONE block/CU.
// GEMM1 uses 32x32x16 (2x FLOP/LDS-byte, half the instrs); GEMM2 16x16x32.
// 32x32 D-layout (HW-verified): col=lane&31, row=(reg&3)+8*(reg>>2)+4*(lane>>5).
__global__ __launch_bounds__(1024, 4) void edge_mlp(
    const float* __restrict__ x, const int* __restrict__ ei,
    const float* __restrict__ ln0_g, const float* __restrict__ ln0_b,
    const short* __restrict__ wb1h, const short* __restrict__ wb1l,
    const float* __restrict__ b1,
    const float* __restrict__ ln1_g, const float* __restrict__ ln1_b,
    const short* __restrict__ wb2h, const short* __restrict__ wb2l,
    const float* __restrict__ b2,
    const float* __restrict__ ln2_g, const float* __restrict__ ln2_b,
    const float* __restrict__ wp, const float* __restrict__ bp,
    const float* __restrict__ ww, const float* __restrict__ bw,
    float* __restrict__ out, int E)
{
    __shared__ __align__(16) short h0h[64 * 264];   // 33.8KB each; ~144KB total
    __shared__ __align__(16) short h0l[64 * 264];
    __shared__ __align__(16) short h1h[64 * 264];
    __shared__ __align__(16) short h1l[64 * 264];
    __shared__ __align__(8) float red[16][64][2];
    __shared__ __align__(8) float stat[64][2];
    __shared__ int sidx[64][2];

    const int tid = threadIdx.x, lane = tid & 63, w = tid >> 6;   // w in 0..15
    const int g = lane >> 4, c15 = lane & 15;
    const long base = (long)blockIdx.x * 64;

    if (tid < 128) {
        const int e = tid >> 1, s = tid & 1;
        const long idx = base + e;
        sidx[e][s] = (idx < E) ? ei[(long)s * E + idx] : 0;
    }
    __syncthreads();

    // ---------- P1: gather + feats + LN0 -> h0h/h0l (wave w: edges w*4..w*4+3) ----------
    {
        const int c = 2 * lane;
        const float ga = ln0_g[c], gb = ln0_g[c + 1], gc = ln0_g[128 + c], gd = ln0_g[129 + c];
        const float ba = ln0_b[c], bb = ln0_b[c + 1], bc = ln0_b[128 + c], bd = ln0_b[129 + c];
        char* hhc = (char*)h0h;
        char* hlc = (char*)h0l;
        #pragma unroll
        for (int e8 = 0; e8 < 4; ++e8) {
            const int e = w * 4 + e8;
            const float2 sv = *reinterpret_cast<const float2*>(&x[(long)sidx[e][0] * 128 + c]);
            const float2 dv = *reinterpret_cast<const float2*>(&x[(long)sidx[e][1] * 128 + c]);
            const float a0 = sv.x + dv.x, a1 = sv.y + dv.y;
            const float m0 = sv.x * dv.x, m1 = sv.y * dv.y;
            float s = a0 + a1 + m0 + m1;
            float q = a0 * a0 + a1 * a1 + m0 * m0 + m1 * m1;
            #pragma unroll
            for (int o = 32; o; o >>= 1) { s += __shfl_xor(s, o); q += __shfl_xor(q, o); }
            const float mu = s * (1.f / 256.f);
            const float rs = rsqrtf(q * (1.f / 256.f) - mu * mu + EPS);
            const bfhl r0 = splitbf((a0 - mu) * rs * ga + ba);
            const bfhl r1 = splitbf((a1 - mu) * rs * gb + bb);
            const bfhl r2 = splitbf((m0 - mu) * rs * gc + bc);
            const bfhl r3 = splitbf((m1 - mu) * rs * gd + bd);
            s16x2 p0h, p0l, p1h, p1l;
            p0h[0] = r0.hi; p0l[0] = r0.lo;
            p0h[1] = r1.hi; p0l[1] = r1.lo;
            p1h[0] = r2.hi; p1l[0] = r2.lo;
            p1h[1] = r3.hi; p1l[1] = r3.lo;
            const int o0 = e * PITCH + 4 * lane;
            const int o1 = e * PITCH + 256 + 4 * lane;
            *reinterpret_cast<s16x2*>(hhc + o0) = p0h;
            *reinterpret_cast<s16x2*>(hhc + o1) = p1h;
            *reinterpret_cast<s16x2*>(hlc + o0) = p0l;
            *reinterpret_cast<s16x2*>(hlc + o1) = p1l;
        }
    }
    __syncthreads();

    // ---------- P2: GEMM1 32x32x16  D[feat 256][edge 64] ----------
    // wave w: ft = w>>1 (feats ft*32..+32), et = w&1 (edges et*32..+32)
    const int ft = w >> 1, et = w & 1;
    const int l31 = lane & 31, lh = lane >> 5;   // lh = k-group
    f32x16 acc1 = {};
    {
        const char* hhc = (const char*)h0h;
        const char* hlc = (const char*)h0l;
        const int e1 = et * 32 + l31;
        const int boff = e1 * PITCH + lh * 16;
        for (int ks = 0; ks < 16; ++ks) {
            const int fo = (ft * 16 + ks) * 512 + lane * 8;
            const s16x8 ah = *reinterpret_cast<const s16x8*>(&wb1h[fo]);
            const s16x8 al = *reinterpret_cast<const s16x8*>(&wb1l[fo]);
            const int off = boff + ks * 32;
            const s16x8 bh = *reinterpret_cast<const s16x8*>(hhc + off);
            const s16x8 bl = *reinterpret_cast<const s16x8*>(hlc + off);
            acc1 = __builtin_amdgcn_mfma_f32_32x32x16_bf16(ah, bl, acc1, 0, 0, 0);
            acc1 = __builtin_amdgcn_mfma_f32_32x32x16_bf16(al, bh, acc1, 0, 0, 0);
            acc1 = __builtin_amdgcn_mfma_f32_32x32x16_bf16(ah, bh, acc1, 0, 0, 0);
        }
    }

    // ---------- P3: bias + LN1 stats + apply + relu -> h1h/h1l ----------
    // lane holds 16 values for edge e1 = et*32+l31, rows r: feat = ft*32 + (r&3) + 8*(r>>2) + 4*lh
    {
        float bi[4][4];   // [g2][i] : feats ft*32 + g2*8 + 4*lh + i
        #pragma unroll
        for (int g2 = 0; g2 < 4; ++g2)
            *reinterpret_cast<float4*>(bi[g2]) =
                *reinterpret_cast<const float4*>(&b1[ft * 32 + g2 * 8 + 4 * lh]);
        float s = 0.f, q = 0.f;
        #pragma unroll
        for (int r = 0; r < 16; ++r) {
            const float v2 = acc1[r] + bi[r >> 2][r & 3];
            acc1[r] = v2; s += v2; q += v2 * v2;
        }
        s += __shfl_xor(s, 32); q += __shfl_xor(q, 32);   // combine row-halves (same edge)
        if (lane < 32) { red[w][et * 32 + lane][0] = s; red[w][et * 32 + lane][1] = q; }
    }
    __syncthreads();
    if (tid < 64) {
        const int hE = tid >> 5;   // which 32-edge half this edge is in
        float S = 0.f, Q = 0.f;
        #pragma unroll
        for (int f = 0; f < 8; ++f) { S += red[2 * f + hE][tid][0]; Q += red[2 * f + hE][tid][1]; }
        const float mu = S * (1.f / 256.f);
        stat[tid][0] = mu;
        stat[tid][1] = rsqrtf(Q * (1.f / 256.f) - mu * mu + EPS);
    }
    __syncthreads();
    {
        const int e1 = et * 32 + l31;
        const float2 st = *reinterpret_cast<const float2*>(stat[e1]);
        char* hhc = (char*)h1h;
        char* hlc = (char*)h1l;
        #pragma unroll
        for (int g2 = 0; g2 < 4; ++g2) {
            const int f0 = ft * 32 + g2 * 8 + 4 * lh;
            float gv[4], bv[4];
            *reinterpret_cast<float4*>(gv) = *reinterpret_cast<const float4*>(&ln1_g[f0]);
            *reinterpret_cast<float4*>(bv) = *reinterpret_cast<const float4*>(&ln1_b[f0]);
            s16x4 ph, pl;
            #pragma unroll
            for (int i = 0; i < 4; ++i) {
                const bfhl rr = splitbf(fmaxf((acc1[g2 * 4 + i] - st.x) * st.y * gv[i] + bv[i], 0.f));
                ph[i] = rr.hi; pl[i] = rr.lo;
            }
            const int off = e1 * PITCH + f0 * 2;
            *reinterpret_cast<s16x4*>(hhc + off) = ph;
            *reinterpret_cast<s16x4*>(hlc + off) = pl;
        }
    }
    __syncthreads();

    // ---------- P4: GEMM2 16x16x32  D[feat 128][edge 64] ----------
    // wave w: ft2 = w>>1, hf = w&1 (edge-tiles 2hf, 2hf+1)
    const int ft2 = w >> 1, hf = w & 1;
    f32x4 acc2[2] = {};
    {
        const char* hhc = (const char*)h1h;
        const char* hlc = (const char*)h1l;
        for (int ks = 0; ks < 8; ++ks) {
            const int fo = (ft2 * 8 + ks) * 512 + lane * 8;
            const s16x8 ah = *reinterpret_cast<const s16x8*>(&wb2h[fo]);
            const s16x8 al = *reinterpret_cast<const s16x8*>(&wb2l[fo]);
            const int kb = ks * 64 + g * 16;
            #pragma unroll
            for (int ntl = 0; ntl < 2; ++ntl) {
                const int e = (2 * hf + ntl) * 16 + c15;
                const int off = e * PITCH + kb;
                const s16x8 bh = *reinterpret_cast<const s16x8*>(hhc + off);
                const s16x8 bl = *reinterpret_cast<const s16x8*>(hlc + off);
                acc2[ntl] = __builtin_amdgcn_mfma_f32_16x16x32_bf16(ah, bl, acc2[ntl], 0, 0, 0);
                acc2[ntl] = __builtin_amdgcn_mfma_f32_16x16x32_bf16(al, bh, acc2[ntl], 0, 0, 0);
                acc2[ntl] = __builtin_amdgcn_mfma_f32_16x16x32_bf16(ah, bh, acc2[ntl], 0, 0, 0);
            }
        }
    }

    // ---------- P5: bias + LN2 stats ----------
    {
        float bi[4];
        *reinterpret_cast<float4*>(bi) = *reinterpret_cast<const float4*>(&b2[ft2 * 16 + g * 4]);
        float s[2], q[2];
        #pragma unroll
        for (int ntl = 0; ntl < 2; ++ntl) {
            s[ntl] = 0.f; q[ntl] = 0.f;
            #pragma unroll
            for (int r = 0; r < 4; ++r) {
                const float v2 = acc2[ntl][r] + bi[r];
                acc2[ntl][r] = v2; s[ntl] += v2; q[ntl] += v2 * v2;
            }
        }
        #pragma unroll
        for (int ntl = 0; ntl < 2; ++ntl) {
            s[ntl] += __shfl_xor(s[ntl], 16); q[ntl] += __shfl_xor(q[ntl], 16);
            s[ntl] += __shfl_xor(s[ntl], 32); q[ntl] += __shfl_xor(q[ntl], 32);
        }
        if ((g >> 1) == hf) {   // lane == edge for nt = g (global), ntl = g&1
            red[w][lane][0] = (g & 1) ? s[1] : s[0];
            red[w][lane][1] = (g & 1) ? q[1] : q[0];
        }
    }
    __syncthreads();
    if (tid < 64) {
        const int hE = tid >> 5;
        float S = 0.f, Q = 0.f;
        #pragma unroll
        for (int w2 = 0; w2 < 16; w2 += 2) { S += red[w2 + hE][tid][0]; Q += red[w2 + hE][tid][1]; }
        const float mu = S * (1.f / 128.f);
        stat[tid][0] = mu;
        stat[tid][1] = rsqrtf(Q * (1.f / 128.f) - mu * mu + EPS);
    }
    __syncthreads();

    // ---------- P6: LN2 apply + relu + heads ----------
    {
        float gv[4], bv[4], pv[4], wv[4];
        *reinterpret_cast<float4*>(gv) = *reinterpret_cast<const float4*>(&ln2_g[ft2 * 16 + g * 4]);
        *reinterpret_cast<float4*>(bv) = *reinterpret_cast<const float4*>(&ln2_b[ft2 * 16 + g * 4]);
        *reinterpret_cast<float4*>(pv) = *reinterpret_cast<const float4*>(&wp[ft2 * 16 + g * 4]);
        *reinterpret_cast<float4*>(wv) = *reinterpret_cast<const float4*>(&ww[ft2 * 16 + g * 4]);
        float pp[2], ws2[2];
        #pragma unroll
        for (int ntl = 0; ntl < 2; ++ntl) {
            const int e = (2 * hf + ntl) * 16 + c15;
            const float2 st = *reinterpret_cast<const float2*>(stat[e]);
            pp[ntl] = 0.f; ws2[ntl] = 0.f;
            #pragma unroll
            for (int r = 0; r < 4; ++r) {
                const float tt = fmaxf((acc2[ntl][r] - st.x) * st.y * gv[r] + bv[r], 0.f);
                pp[ntl] += tt * pv[r]; ws2[ntl] += tt * wv[r];
            }
        }
        #pragma unroll
        for (int ntl = 0; ntl < 2; ++ntl) {
            pp[ntl] += __shfl_xor(pp[ntl], 16); ws2[ntl] += __shfl_xor(ws2[ntl], 16);
            pp[ntl] += __shfl_xor(pp[ntl], 32); ws2[ntl] += __shfl_xor(ws2[ntl], 32);
        }
        if ((g >> 1) == hf) {
            red[w][lane][0] = (g & 1) ? pp[1] : pp[0];
            red[w][lane][1] = (g & 1) ? ws2[1] : ws2[0];
        }
    }
    __syncthreads();
    if (tid < 64 && base + tid < E) {
        const int hE = tid >> 5;
        float P = bp[0], W = bw[0];
        #pragma unroll
        for (int w2 = 0; w2 < 16; w2 += 2) { P += red[w2 + hE][tid][0]; W += red[w2 + hE][tid][1]; }
        out[base + tid] = P;                         // logits
        out[(long)E + base + tid] = fmaxf(W, 0.f);   // relu'd weights
    }
}

extern "C" void kernel_launch(void* const* d_in, const int* in_sizes, int n_in,
                              void* d_out, int out_size, void* d_ws, size_t ws_size,
                              hipStream_t stream) {
    const float* x     = (const float*)d_in[0];
    const int*   ei    = (const int*)  d_in[1];
    const float* ln0_g = (const float*)d_in[2];
    const float* ln0_b = (const float*)d_in[3];
    const float* w1    = (const float*)d_in[4];
    const float* b1    = (const float*)d_in[5];
    const float* ln1_g = (const float*)d_in[6];
    const float* ln1_b = (const float*)d_in[7];
    const float* w2    = (const float*)d_in[8];
    const float* b2    = (const float*)d_in[9];
    const float* ln2_g = (const float*)d_in[10];
    const float* ln2_b = (const float*)d_in[11];
    const float* wp    = (const float*)d_in[12];
    const float* bp    = (const float*)d_in[13];
    const float* ww    = (const float*)d_in[14];
    const float* bw    = (const float*)d_in[15];

    short* wb1h = (short*)d_ws;             // 128 frags * 512
    short* wb1l = wb1h + 128 * 512;
    short* wb2h = wb1l + 128 * 512;         // 64 frags * 512
    short* wb2l = wb2h + 64 * 512;          // total 384KB

    const int E = in_sizes[1] / 2;
    prep_weights<<<48, 256, 0, stream>>>(w1, w2, wb1h, wb1l, wb2h, wb2l);
    edge_mlp<<<(E + 63) / 64, 1024, 0, stream>>>(x, ei, ln0_g, ln0_b, wb1h, wb1l, b1,
                                                 ln1_g, ln1_b, wb2h, wb2l, b2, ln2_g, ln2_b,
                                                 wp, bp, ww, bw, (float*)d_out, E);
}

// Round 16
// 839.697 us; speedup vs baseline: 2.9624x; 1.0453x over previous
//
#include <hip/hip_runtime.h>

#define EPS 1e-5f
#define PITCH 528   // bytes per LDS row (264 bf16); 132 words % 32 banks = 4

typedef __attribute__((ext_vector_type(8))) short s16x8;
typedef __attribute__((ext_vector_type(4))) short s16x4;
typedef __attribute__((ext_vector_type(2))) short s16x2;
typedef __attribute__((ext_vector_type(16))) float f32x16;

static __device__ __forceinline__ short f2bf(float x) {
    union { float f; unsigned u; } v; v.f = x;
    return (short)((v.u + 0x7fffu + ((v.u >> 16) & 1u)) >> 16);  // RNE
}
static __device__ __forceinline__ float bf2f(short h) {
    union { float f; unsigned u; } v; v.u = ((unsigned)(unsigned short)h) << 16;
    return v.f;
}
struct bfhl { short hi, lo; };
// exact split: x = hi + lo + r, |r| <= 2^-17 |x|; bf16 lo never denormal
static __device__ __forceinline__ bfhl splitbf(float x) {
    bfhl r; r.hi = f2bf(x); r.lo = f2bf(x - bf2f(r.hi)); return r;
}

// ---- prep: repack weights into split-bf16 32x32x16 MFMA A-fragments of W^T ----
// w1 (256x256): frag(ft 0..7, ks 0..15): lane l, elem j <- W1[ks*16+(l>>5)*8+j][ft*32+(l&31)]
// w2 (256x128): frag(ft2 0..3, ks 0..15): lane l, elem j <- W2[ks*16+(l>>5)*8+j][ft2*32+(l&31)]
__global__ __launch_bounds__(256) void prep_weights(
    const float* __restrict__ w1, const float* __restrict__ w2,
    short* __restrict__ wb1h, short* __restrict__ wb1l,
    short* __restrict__ wb2h, short* __restrict__ wb2l)
{
    const int t = blockIdx.x * 256 + threadIdx.x;
    const int lane = t & 63, frag = t >> 6;
    short hi[8], lo[8];
    if (frag < 128) {                 // w1: 8 ft x 16 ks
        const int row0 = (frag & 15) * 16 + (lane >> 5) * 8;
        const int col = (frag >> 4) * 32 + (lane & 31);
        #pragma unroll
        for (int j = 0; j < 8; ++j) {
            const bfhl r = splitbf(w1[(row0 + j) * 256 + col]);
            hi[j] = r.hi; lo[j] = r.lo;
        }
        *reinterpret_cast<s16x8*>(&wb1h[frag * 512 + lane * 8]) = *reinterpret_cast<s16x8*>(hi);
        *reinterpret_cast<s16x8*>(&wb1l[frag * 512 + lane * 8]) = *reinterpret_cast<s16x8*>(lo);
    } else if (frag < 192) {          // w2: 4 ft2 x 16 ks
        const int f = frag - 128;
        const int row0 = (f & 15) * 16 + (lane >> 5) * 8;
        const int col = (f >> 4) * 32 + (lane & 31);
        #pragma unroll
        for (int j = 0; j < 8; ++j) {
            const bfhl r = splitbf(w2[(row0 + j) * 128 + col]);
            hi[j] = r.hi; lo[j] = r.lo;
        }
        *reinterpret_cast<s16x8*>(&wb2h[f * 512 + lane * 8]) = *reinterpret_cast<s16x8*>(hi);
        *reinterpret_cast<s16x8*>(&wb2l[f * 512 + lane * 8]) = *reinterpret_cast<s16x8*>(lo);
    }
}

// ---- fused MLP: 128 edges/block, 1024 thr (16 waves), all-32x32 split-bf16 GEMMs ----
// acc = Wh·Hl + Wl·Hh + Wh·Hh  (dropped Wl·Hl <= 2^-17 rel)
// HARD CONSTRAINT (empirical, R2-R12): LDS > 80KB so only ONE block/CU resident.
// h1 OVERLAYS h0 (hh/hl reused) -- safe by construction (h1 writes are two
// barriers after the last h0 read); this also tests whether R10's "aliasing"
// failure was really the 2-blocks/CU confound (all failures had 2 blocks/CU).
// 128 edges/block halves per-edge weight-L2 traffic and barrier count.
__global__ __launch_bounds__(1024, 4) void edge_mlp(
    const float* __restrict__ x, const int* __restrict__ ei,
    const float* __restrict__ ln0_g, const float* __restrict__ ln0_b,
    const short* __restrict__ wb1h, const short* __restrict__ wb1l,
    const float* __restrict__ b1,
    const float* __restrict__ ln1_g, const float* __restrict__ ln1_b,
    const short* __restrict__ wb2h, const short* __restrict__ wb2l,
    const float* __restrict__ b2,
    const float* __restrict__ ln2_g, const float* __restrict__ ln2_b,
    const float* __restrict__ wp, const float* __restrict__ bp,
    const float* __restrict__ ww, const float* __restrict__ bw,
    float* __restrict__ out, int E)
{
    __shared__ __align__(16) short hh[128 * 264];   // 66KB: h0 hi, then h1 hi (overlay)
    __shared__ __align__(16) short hl[128 * 264];   // 66KB: h0 lo, then h1 lo
    __shared__ __align__(8) float red[16][128][2];  // 16KB
    __shared__ __align__(8) float stat[128][2];
    __shared__ int sidx[128][2];                    // total ~150KB -> 1 block/CU

    const int tid = threadIdx.x, lane = tid & 63, w = tid >> 6;   // w in 0..15
    const int l31 = lane & 31, lh = lane >> 5;
    const long base = (long)blockIdx.x * 128;

    if (tid < 256) {
        const int e = tid >> 1, s = tid & 1;
        const long idx = base + e;
        sidx[e][s] = (idx < E) ? ei[(long)s * E + idx] : 0;
    }
    __syncthreads();

    // ---------- P1: gather + feats + LN0 -> h0 (wave w: edges w*8..w*8+7) ----------
    {
        const int c = 2 * lane;
        const float ga = ln0_g[c], gb = ln0_g[c + 1], gc = ln0_g[128 + c], gd = ln0_g[129 + c];
        const float ba = ln0_b[c], bb = ln0_b[c + 1], bc = ln0_b[128 + c], bd = ln0_b[129 + c];
        char* hhc = (char*)hh;
        char* hlc = (char*)hl;
        #pragma unroll
        for (int e8 = 0; e8 < 8; ++e8) {
            const int e = w * 8 + e8;
            const float2 sv = *reinterpret_cast<const float2*>(&x[(long)sidx[e][0] * 128 + c]);
            const float2 dv = *reinterpret_cast<const float2*>(&x[(long)sidx[e][1] * 128 + c]);
            const float a0 = sv.x + dv.x, a1 = sv.y + dv.y;
            const float m0 = sv.x * dv.x, m1 = sv.y * dv.y;
            float s = a0 + a1 + m0 + m1;
            float q = a0 * a0 + a1 * a1 + m0 * m0 + m1 * m1;
            #pragma unroll
            for (int o = 32; o; o >>= 1) { s += __shfl_xor(s, o); q += __shfl_xor(q, o); }
            const float mu = s * (1.f / 256.f);
            const float rs = rsqrtf(q * (1.f / 256.f) - mu * mu + EPS);
            const bfhl r0 = splitbf((a0 - mu) * rs * ga + ba);
            const bfhl r1 = splitbf((a1 - mu) * rs * gb + bb);
            const bfhl r2 = splitbf((m0 - mu) * rs * gc + bc);
            const bfhl r3 = splitbf((m1 - mu) * rs * gd + bd);
            s16x2 p0h, p0l, p1h, p1l;
            p0h[0] = r0.hi; p0l[0] = r0.lo;
            p0h[1] = r1.hi; p0l[1] = r1.lo;
            p1h[0] = r2.hi; p1l[0] = r2.lo;
            p1h[1] = r3.hi; p1l[1] = r3.lo;
            const int o0 = e * PITCH + 4 * lane;
            const int o1 = e * PITCH + 256 + 4 * lane;
            *reinterpret_cast<s16x2*>(hhc + o0) = p0h;
            *reinterpret_cast<s16x2*>(hhc + o1) = p1h;
            *reinterpret_cast<s16x2*>(hlc + o0) = p0l;
            *reinterpret_cast<s16x2*>(hlc + o1) = p1l;
        }
    }
    __syncthreads();

    // ---------- P2: GEMM1 32x32x16  D[feat 256][edge 128] ----------
    // wave w: ft = w>>1 (feats ft*32..+32), ep = w&1 (edges ep*64..+64, two 32-tiles)
    const int ft = w >> 1, ep = w & 1;
    f32x16 acc1[2] = {};
    {
        const char* hhc = (const char*)hh;
        const char* hlc = (const char*)hl;
        const int boffA = (ep * 64 + l31) * PITCH + lh * 16;
        const int boffB = (ep * 64 + 32 + l31) * PITCH + lh * 16;
        for (int ks = 0; ks < 16; ++ks) {
            const int fo = (ft * 16 + ks) * 512 + lane * 8;
            const s16x8 ah = *reinterpret_cast<const s16x8*>(&wb1h[fo]);
            const s16x8 al = *reinterpret_cast<const s16x8*>(&wb1l[fo]);
            const int offA = boffA + ks * 32;
            const s16x8 bhA = *reinterpret_cast<const s16x8*>(hhc + offA);
            const s16x8 blA = *reinterpret_cast<const s16x8*>(hlc + offA);
            acc1[0] = __builtin_amdgcn_mfma_f32_32x32x16_bf16(ah, blA, acc1[0], 0, 0, 0);
            acc1[0] = __builtin_amdgcn_mfma_f32_32x32x16_bf16(al, bhA, acc1[0], 0, 0, 0);
            acc1[0] = __builtin_amdgcn_mfma_f32_32x32x16_bf16(ah, bhA, acc1[0], 0, 0, 0);
            const int offB = boffB + ks * 32;
            const s16x8 bhB = *reinterpret_cast<const s16x8*>(hhc + offB);
            const s16x8 blB = *reinterpret_cast<const s16x8*>(hlc + offB);
            acc1[1] = __builtin_amdgcn_mfma_f32_32x32x16_bf16(ah, blB, acc1[1], 0, 0, 0);
            acc1[1] = __builtin_amdgcn_mfma_f32_32x32x16_bf16(al, bhB, acc1[1], 0, 0, 0);
            acc1[1] = __builtin_amdgcn_mfma_f32_32x32x16_bf16(ah, bhB, acc1[1], 0, 0, 0);
        }
    }

    // ---------- P3: bias + LN1 stats ----------
    // lane holds 16 vals/edge-tile; feat = ft*32 + (r&3) + 8*(r>>2) + 4*lh; edge = ep*64 + t*32 + l31
    {
        float bi[4][4];
        #pragma unroll
        for (int g2 = 0; g2 < 4; ++g2)
            *reinterpret_cast<float4*>(bi[g2]) =
                *reinterpret_cast<const float4*>(&b1[ft * 32 + g2 * 8 + 4 * lh]);
        #pragma unroll
        for (int t = 0; t < 2; ++t) {
            float s = 0.f, q = 0.f;
            #pragma unroll
            for (int r = 0; r < 16; ++r) {
                const float v2 = acc1[t][r] + bi[r >> 2][r & 3];
                acc1[t][r] = v2; s += v2; q += v2 * v2;
            }
            s += __shfl_xor(s, 32); q += __shfl_xor(q, 32);   // combine lh halves (same edge)
            if (lane < 32) {
                red[w][ep * 64 + t * 32 + lane][0] = s;
                red[w][ep * 64 + t * 32 + lane][1] = q;
            }
        }
    }
    __syncthreads();
    if (tid < 128) {
        const int hE = tid >> 6;   // which 64-edge half
        float S = 0.f, Q = 0.f;
        #pragma unroll
        for (int f = 0; f < 8; ++f) { S += red[2 * f + hE][tid][0]; Q += red[2 * f + hE][tid][1]; }
        const float mu = S * (1.f / 256.f);
        stat[tid][0] = mu;
        stat[tid][1] = rsqrtf(Q * (1.f / 256.f) - mu * mu + EPS);
    }
    __syncthreads();
    // apply + relu -> h1 (overlays h0; all h0 reads finished two barriers ago)
    {
        char* hhc = (char*)hh;
        char* hlc = (char*)hl;
        #pragma unroll
        for (int t = 0; t < 2; ++t) {
            const int e = ep * 64 + t * 32 + l31;
            const float2 st = *reinterpret_cast<const float2*>(stat[e]);
            #pragma unroll
            for (int g2 = 0; g2 < 4; ++g2) {
                const int f0 = ft * 32 + g2 * 8 + 4 * lh;
                float gv[4], bv[4];
                *reinterpret_cast<float4*>(gv) = *reinterpret_cast<const float4*>(&ln1_g[f0]);
                *reinterpret_cast<float4*>(bv) = *reinterpret_cast<const float4*>(&ln1_b[f0]);
                s16x4 ph, pl;
                #pragma unroll
                for (int i = 0; i < 4; ++i) {
                    const bfhl rr = splitbf(fmaxf((acc1[t][g2 * 4 + i] - st.x) * st.y * gv[i] + bv[i], 0.f));
                    ph[i] = rr.hi; pl[i] = rr.lo;
                }
                const int off = e * PITCH + f0 * 2;
                *reinterpret_cast<s16x4*>(hhc + off) = ph;
                *reinterpret_cast<s16x4*>(hlc + off) = pl;
            }
        }
    }
    __syncthreads();

    // ---------- P4: GEMM2 32x32x16  D[feat 128][edge 128] ----------
    // wave w: ft2 = w>>2 (0..3), et2 = w&3 (edges et2*32..+32); K=256 -> 16 ks
    const int ft2 = w >> 2, et2 = w & 3;
    const int e2 = et2 * 32 + l31;
    f32x16 acc2 = {};
    {
        const char* hhc = (const char*)hh;
        const char* hlc = (const char*)hl;
        const int boff2 = e2 * PITCH + lh * 16;
        for (int ks = 0; ks < 16; ++ks) {
            const int fo = (ft2 * 16 + ks) * 512 + lane * 8;
            const s16x8 ah = *reinterpret_cast<const s16x8*>(&wb2h[fo]);
            const s16x8 al = *reinterpret_cast<const s16x8*>(&wb2l[fo]);
            const int off = boff2 + ks * 32;
            const s16x8 bh = *reinterpret_cast<const s16x8*>(hhc + off);
            const s16x8 bl = *reinterpret_cast<const s16x8*>(hlc + off);
            acc2 = __builtin_amdgcn_mfma_f32_32x32x16_bf16(ah, bl, acc2, 0, 0, 0);
            acc2 = __builtin_amdgcn_mfma_f32_32x32x16_bf16(al, bh, acc2, 0, 0, 0);
            acc2 = __builtin_amdgcn_mfma_f32_32x32x16_bf16(ah, bh, acc2, 0, 0, 0);
        }
    }

    // ---------- P5: bias + LN2 stats ----------
    {
        float bi[4][4];
        #pragma unroll
        for (int g2 = 0; g2 < 4; ++g2)
            *reinterpret_cast<float4*>(bi[g2]) =
                *reinterpret_cast<const float4*>(&b2[ft2 * 32 + g2 * 8 + 4 * lh]);
        float s = 0.f, q = 0.f;
        #pragma unroll
        for (int r = 0; r < 16; ++r) {
            const float v2 = acc2[r] + bi[r >> 2][r & 3];
            acc2[r] = v2; s += v2; q += v2 * v2;
        }
        s += __shfl_xor(s, 32); q += __shfl_xor(q, 32);
        if (lane < 32) { red[w][et2 * 32 + lane][0] = s; red[w][et2 * 32 + lane][1] = q; }
    }
    __syncthreads();
    if (tid < 128) {
        const int q5 = tid >> 5;   // which 32-edge quarter
        float S = 0.f, Q = 0.f;
        #pragma unroll
        for (int f2 = 0; f2 < 4; ++f2) { S += red[4 * f2 + q5][tid][0]; Q += red[4 * f2 + q5][tid][1]; }
        const float mu = S * (1.f / 128.f);
        stat[tid][0] = mu;
        stat[tid][1] = rsqrtf(Q * (1.f / 128.f) - mu * mu + EPS);
    }
    __syncthreads();

    // ---------- P6: LN2 apply + relu + heads ----------
    {
        const float2 st = *reinterpret_cast<const float2*>(stat[e2]);
        float pp = 0.f, ws2 = 0.f;
        #pragma unroll
        for (int g2 = 0; g2 < 4; ++g2) {
            const int f0 = ft2 * 32 + g2 * 8 + 4 * lh;
            float gv[4], bv[4], pv[4], wv[4];
            *reinterpret_cast<float4*>(gv) = *reinterpret_cast<const float4*>(&ln2_g[f0]);
            *reinterpret_cast<float4*>(bv) = *reinterpret_cast<const float4*>(&ln2_b[f0]);
            *reinterpret_cast<float4*>(pv) = *reinterpret_cast<const float4*>(&wp[f0]);
            *reinterpret_cast<float4*>(wv) = *reinterpret_cast<const float4*>(&ww[f0]);
            #pragma unroll
            for (int i = 0; i < 4; ++i) {
                const float t = fmaxf((acc2[g2 * 4 + i] - st.x) * st.y * gv[i] + bv[i], 0.f);
                pp += t * pv[i]; ws2 += t * wv[i];
            }
        }
        pp += __shfl_xor(pp, 32); ws2 += __shfl_xor(ws2, 32);
        if (lane < 32) { red[w][et2 * 32 + lane][0] = pp; red[w][et2 * 32 + lane][1] = ws2; }
    }
    __syncthreads();
    if (tid < 128 && base + tid < E) {
        const int q5 = tid >> 5;
        float P = bp[0], W = bw[0];
        #pragma unroll
        for (int f2 = 0; f2 < 4; ++f2) { P += red[4 * f2 + q5][tid][0]; W += red[4 * f2 + q5][tid][1]; }
        out[base + tid] = P;                         // logits
        out[(long)E + base + tid] = fmaxf(W, 0.f);   // relu'd weights
    }
}

extern "C" void kernel_launch(void* const* d_in, const int* in_sizes, int n_in,
                              void* d_out, int out_size, void* d_ws, size_t ws_size,
                              hipStream_t stream) {
    const float* x     = (const float*)d_in[0];
    const int*   ei    = (const int*)  d_in[1];
    const float* ln0_g = (const float*)d_in[2];
    const float* ln0_b = (const float*)d_in[3];
    const float* w1    = (const float*)d_in[4];
    const float* b1    = (const float*)d_in[5];
    const float* ln1_g = (const float*)d_in[6];
    const float* ln1_b = (const float*)d_in[7];
    const float* w2    = (const float*)d_in[8];
    const float* b2    = (const float*)d_in[9];
    const float* ln2_g = (const float*)d_in[10];
    const float* ln2_b = (const float*)d_in[11];
    const float* wp    = (const float*)d_in[12];
    const float* bp    = (const float*)d_in[13];
    const float* ww    = (const float*)d_in[14];
    const float* bw    = (const float*)d_in[15];

    short* wb1h = (short*)d_ws;             // 128 frags * 512
    short* wb1l = wb1h + 128 * 512;
    short* wb2h = wb1l + 128 * 512;         // 64 frags * 512
    short* wb2l = wb2h + 64 * 512;          // total 384KB

    const int E = in_sizes[1] / 2;
    prep_weights<<<48, 256, 0, stream>>>(w1, w2, wb1h, wb1l, wb2h, wb2l);
    edge_mlp<<<(E + 127) / 128, 1024, 0, stream>>>(x, ei, ln0_g, ln0_b, wb1h, wb1l, b1,
                                                   ln1_g, ln1_b, wb2h, wb2l, b2, ln2_g, ln2_b,
                                                   wp, bp, ww, bw, (float*)d_out, E);
}